// Round 1
// baseline (192.849 us; speedup 1.0000x reference)
//
#include <hip/hip_runtime.h>

// t2[b] = (S10*S11 - S01*S00)^2 where Sxy = x_A^T S_AB[b] y_B
// NMOL=4096 blocks, 256 threads (4 waves). Wave w handles rows m in
// [64w, 64w+64); lane l handles columns [4l, 4l+4) via float4.
// Bilinearity: each lane accumulates hS/lS partials for its (m,n) chunk,
// folds with hB/lB into 4 scalars, then block-reduces.

#define NAO 256

__global__ __launch_bounds__(256) void sf_rate_kernel(
    const float* __restrict__ hA, const float* __restrict__ lA,
    const float* __restrict__ hB, const float* __restrict__ lB,
    const float* __restrict__ S,  float* __restrict__ out)
{
    const int b    = blockIdx.x;
    const int t    = threadIdx.x;
    const int wave = t >> 6;
    const int lane = t & 63;

    __shared__ float sh_hA[NAO];
    __shared__ float sh_lA[NAO];
    __shared__ float red[4][4];

    // Stage the two A-vectors for this molecule (coalesced, one load each).
    sh_hA[t] = hA[b * NAO + t];
    sh_lA[t] = lA[b * NAO + t];
    __syncthreads();

    // S row-major [m][n]; as float4: index m*64 + lane.
    const float4* S4 = reinterpret_cast<const float4*>(S + (size_t)b * NAO * NAO);

    float4 ah = make_float4(0.f, 0.f, 0.f, 0.f);  // partial hS for 4 columns
    float4 al = make_float4(0.f, 0.f, 0.f, 0.f);  // partial lS for 4 columns

    const int m0 = wave * 64;
    #pragma unroll 8
    for (int i = 0; i < 64; ++i) {
        const int m = m0 + i;
        const float4 s4 = S4[m * 64 + lane];      // 64 lanes x 16B contiguous
        const float h = sh_hA[m];                 // LDS broadcast
        const float l = sh_lA[m];
        ah.x = fmaf(h, s4.x, ah.x); ah.y = fmaf(h, s4.y, ah.y);
        ah.z = fmaf(h, s4.z, ah.z); ah.w = fmaf(h, s4.w, ah.w);
        al.x = fmaf(l, s4.x, al.x); al.y = fmaf(l, s4.y, al.y);
        al.z = fmaf(l, s4.z, al.z); al.w = fmaf(l, s4.w, al.w);
    }

    // Fold with B-vectors for this lane's 4 columns.
    const float4 hb4 = reinterpret_cast<const float4*>(hB + b * NAO)[lane];
    const float4 lb4 = reinterpret_cast<const float4*>(lB + b * NAO)[lane];

    float d00 = ah.x * hb4.x + ah.y * hb4.y + ah.z * hb4.z + ah.w * hb4.w;
    float d01 = ah.x * lb4.x + ah.y * lb4.y + ah.z * lb4.z + ah.w * lb4.w;
    float d10 = al.x * hb4.x + al.y * hb4.y + al.z * hb4.z + al.w * hb4.w;
    float d11 = al.x * lb4.x + al.y * lb4.y + al.z * lb4.z + al.w * lb4.w;

    // Wave-level butterfly reduce (64 lanes).
    #pragma unroll
    for (int off = 32; off > 0; off >>= 1) {
        d00 += __shfl_down(d00, off);
        d01 += __shfl_down(d01, off);
        d10 += __shfl_down(d10, off);
        d11 += __shfl_down(d11, off);
    }
    if (lane == 0) {
        red[wave][0] = d00; red[wave][1] = d01;
        red[wave][2] = d10; red[wave][3] = d11;
    }
    __syncthreads();

    if (t == 0) {
        float S00 = 0.f, S01 = 0.f, S10 = 0.f, S11 = 0.f;
        #pragma unroll
        for (int w = 0; w < 4; ++w) {
            S00 += red[w][0]; S01 += red[w][1];
            S10 += red[w][2]; S11 += red[w][3];
        }
        const float v = S10 * S11 - S01 * S00;
        out[b] = v * v;
    }
}

extern "C" void kernel_launch(void* const* d_in, const int* in_sizes, int n_in,
                              void* d_out, int out_size, void* d_ws, size_t ws_size,
                              hipStream_t stream) {
    const float* hA = (const float*)d_in[0];
    const float* lA = (const float*)d_in[1];
    const float* hB = (const float*)d_in[2];
    const float* lB = (const float*)d_in[3];
    const float* S  = (const float*)d_in[4];
    float* out = (float*)d_out;

    const int nmol = out_size;  // 4096
    sf_rate_kernel<<<nmol, 256, 0, stream>>>(hA, lA, hB, lB, S, out);
}

// Round 2
// 170.484 us; speedup vs baseline: 1.1312x; 1.1312x over previous
//
#include <hip/hip_runtime.h>

// t2[b] = (S10*S11 - S01*S00)^2 where Sxy = x_A^T S_AB[b] y_B
// NMOL=4096 blocks, 256 threads (4 waves). Wave w handles rows m in
// [64w, 64w+64); lane l handles columns [4l, 4l+4) via float4.
// R1: batch 8 nontemporal dwordx4 loads per inner step for deeper MLP;
// S is a pure 1 GB read-once stream (4x L3) -> nt avoids cache churn.

#define NAO 256

typedef float f32x4 __attribute__((ext_vector_type(4)));

__global__ __launch_bounds__(256) void sf_rate_kernel(
    const float* __restrict__ hA, const float* __restrict__ lA,
    const float* __restrict__ hB, const float* __restrict__ lB,
    const float* __restrict__ S,  float* __restrict__ out)
{
    const int b    = blockIdx.x;
    const int t    = threadIdx.x;
    const int wave = t >> 6;
    const int lane = t & 63;

    __shared__ float sh_hA[NAO];
    __shared__ float sh_lA[NAO];
    __shared__ float red[4][4];

    sh_hA[t] = hA[b * NAO + t];
    sh_lA[t] = lA[b * NAO + t];
    __syncthreads();

    // S row-major [m][n]; as f32x4: index m*64 + lane.
    const f32x4* S4 = reinterpret_cast<const f32x4*>(S + (size_t)b * NAO * NAO);

    f32x4 ah = (f32x4)(0.f);  // partial hS for this lane's 4 columns
    f32x4 al = (f32x4)(0.f);  // partial lS

    const int m0 = wave * 64;
    // 64 rows per wave = 8 batches x 8 rows; 8 loads in flight per batch.
    for (int batch = 0; batch < 8; ++batch) {
        const int mb = m0 + batch * 8;
        f32x4 s[8];
        #pragma unroll
        for (int j = 0; j < 8; ++j)
            s[j] = __builtin_nontemporal_load(&S4[(mb + j) * 64 + lane]);
        #pragma unroll
        for (int j = 0; j < 8; ++j) {
            const float h = sh_hA[mb + j];   // LDS broadcast
            const float l = sh_lA[mb + j];
            ah += h * s[j];                  // contracts to v_fma_f32
            al += l * s[j];
        }
    }

    const f32x4 hb4 = reinterpret_cast<const f32x4*>(hB + b * NAO)[lane];
    const f32x4 lb4 = reinterpret_cast<const f32x4*>(lB + b * NAO)[lane];

    float d00 = ah.x * hb4.x + ah.y * hb4.y + ah.z * hb4.z + ah.w * hb4.w;
    float d01 = ah.x * lb4.x + ah.y * lb4.y + ah.z * lb4.z + ah.w * lb4.w;
    float d10 = al.x * hb4.x + al.y * hb4.y + al.z * hb4.z + al.w * hb4.w;
    float d11 = al.x * lb4.x + al.y * lb4.y + al.z * lb4.z + al.w * lb4.w;

    #pragma unroll
    for (int off = 32; off > 0; off >>= 1) {
        d00 += __shfl_down(d00, off);
        d01 += __shfl_down(d01, off);
        d10 += __shfl_down(d10, off);
        d11 += __shfl_down(d11, off);
    }
    if (lane == 0) {
        red[wave][0] = d00; red[wave][1] = d01;
        red[wave][2] = d10; red[wave][3] = d11;
    }
    __syncthreads();

    if (t == 0) {
        float S00 = 0.f, S01 = 0.f, S10 = 0.f, S11 = 0.f;
        #pragma unroll
        for (int w = 0; w < 4; ++w) {
            S00 += red[w][0]; S01 += red[w][1];
            S10 += red[w][2]; S11 += red[w][3];
        }
        const float v = S10 * S11 - S01 * S00;
        out[b] = v * v;
    }
}

extern "C" void kernel_launch(void* const* d_in, const int* in_sizes, int n_in,
                              void* d_out, int out_size, void* d_ws, size_t ws_size,
                              hipStream_t stream) {
    const float* hA = (const float*)d_in[0];
    const float* lA = (const float*)d_in[1];
    const float* hB = (const float*)d_in[2];
    const float* lB = (const float*)d_in[3];
    const float* S  = (const float*)d_in[4];
    float* out = (float*)d_out;

    const int nmol = out_size;  // 4096
    sf_rate_kernel<<<nmol, 256, 0, stream>>>(hA, lA, hB, lB, S, out);
}